// Round 2
// baseline (306.859 us; speedup 1.0000x reference)
//
#include <hip/hip_runtime.h>
#include <math.h>

#define IC_   2048
#define NC_   16
#define OD_   16
#define ID_   8
#define B_    128
#define BB_   8            // batch elements per block (W register reuse factor)
#define NW_   4            // waves per block
#define LOG2E_ 1.4426950408889634f

// One routing pass, b-batched.
// Lane layout: lane l owns c = l&15, o-group og = l>>4 (o = og*4 + j, j=0..3).
// W[i] fragment per lane: 32 consecutive floats (c*128 + og*32) -> 8 float4 regs,
// reused across BB_ batch elements. Logit dot over o: 3 fma in-lane + xor16/xor32.
// Softmax Z over c: xor1/2/4/8 within a row of 16.
template<bool UNIFORM, int CH>
__global__ __launch_bounds__(256)
void caps_pass(const float* __restrict__ x, const float* __restrict__ W,
               const float* __restrict__ vs, float* __restrict__ s_part) {
  constexpr int ICPB = IC_ / CH;
  const int bg   = blockIdx.x;
  const int ch   = blockIdx.y;
  const int tid  = threadIdx.x;
  const int wid  = tid >> 6;
  const int lane = tid & 63;
  const int c    = lane & 15;
  const int og   = lane >> 4;
  const int cobase = c * 16 + og * 4;

  // v (pre-scaled by log2e): one float4 per batch element
  float4 vr[BB_];
  if (!UNIFORM) {
#pragma unroll
    for (int bb = 0; bb < BB_; ++bb)
      vr[bb] = *(const float4*)(vs + (size_t)(bg * BB_ + bb) * 256 + cobase);
  }

  float4 acc[BB_];
#pragma unroll
  for (int bb = 0; bb < BB_; ++bb) acc[bb] = make_float4(0.f, 0.f, 0.f, 0.f);

  const int ibase = ch * ICPB;

  for (int t = 0; t < ICPB / NW_; ++t) {
    const int i = ibase + t * NW_ + wid;
    const float* wr = W + (size_t)i * (NC_ * OD_ * ID_) + c * 128 + og * 32;
    const float4 w0 = ((const float4*)wr)[0];
    const float4 w1 = ((const float4*)wr)[1];
    const float4 w2 = ((const float4*)wr)[2];
    const float4 w3 = ((const float4*)wr)[3];
    const float4 w4 = ((const float4*)wr)[4];
    const float4 w5 = ((const float4*)wr)[5];
    const float4 w6 = ((const float4*)wr)[6];
    const float4 w7 = ((const float4*)wr)[7];

#pragma unroll
    for (int bb = 0; bb < BB_; ++bb) {
      // x[b,i,0..7] is lane-uniform -> scalar loads
      const float* xp = x + ((size_t)(bg * BB_ + bb) * IC_ + i) * ID_;
      const float4 x0 = *(const float4*)xp;
      const float4 x1 = *(const float4*)(xp + 4);

      const float u0 = w0.x*x0.x + w0.y*x0.y + w0.z*x0.z + w0.w*x0.w
                     + w1.x*x1.x + w1.y*x1.y + w1.z*x1.z + w1.w*x1.w;
      const float u1 = w2.x*x0.x + w2.y*x0.y + w2.z*x0.z + w2.w*x0.w
                     + w3.x*x1.x + w3.y*x1.y + w3.z*x1.z + w3.w*x1.w;
      const float u2 = w4.x*x0.x + w4.y*x0.y + w4.z*x0.z + w4.w*x0.w
                     + w5.x*x1.x + w5.y*x1.y + w5.z*x1.z + w5.w*x1.w;
      const float u3 = w6.x*x0.x + w6.y*x0.y + w6.z*x0.z + w6.w*x0.w
                     + w7.x*x1.x + w7.y*x1.y + w7.z*x1.z + w7.w*x1.w;

      if (UNIFORM) {
        acc[bb].x += u0; acc[bb].y += u1; acc[bb].z += u2; acc[bb].w += u3;
      } else {
        // logit (already x log2e via pre-scaled v)
        float d = u0*vr[bb].x + u1*vr[bb].y + u2*vr[bb].z + u3*vr[bb].w;
        d += __shfl_xor(d, 16);
        d += __shfl_xor(d, 32);
        const float e = __builtin_amdgcn_exp2f(d);   // |logit| ~1e-2, no max-sub needed
        float Z = e;
        Z += __shfl_xor(Z, 1);
        Z += __shfl_xor(Z, 2);
        Z += __shfl_xor(Z, 4);
        Z += __shfl_xor(Z, 8);
        const float wgt = e * __builtin_amdgcn_rcpf(Z);
        acc[bb].x += wgt*u0; acc[bb].y += wgt*u1; acc[bb].z += wgt*u2; acc[bb].w += wgt*u3;
      }
    }
  }

  // cross-wave reduce in LDS, then one coalesced partial write per (b, co)
  __shared__ float red[NW_][BB_ * 256];
#pragma unroll
  for (int bb = 0; bb < BB_; ++bb)
    *(float4*)&red[wid][bb * 256 + cobase] = acc[bb];
  __syncthreads();

#pragma unroll
  for (int k = 0; k < BB_; ++k) {
    const int idx = k * 256 + tid;
    const float s = red[0][idx] + red[1][idx] + red[2][idx] + red[3][idx];
    s_part[((size_t)(bg * BB_ + k) * CH + ch) * 256 + tid] = s;
  }
}

// Reduce partials over nch chunks, squash, produce v / scaled-v / output.
// mode 0: vraw = v1, vs_next = v1*log2e            (scale = 1/16)
// mode 1: vs_next = (v1raw + v2)*log2e             (scale = 1)
// mode 2: out = v3                                 (scale = 1)
__global__ __launch_bounds__(256)
void caps_reduce(const float* __restrict__ s_part, float* __restrict__ vraw,
                 float* __restrict__ vs_next, float* __restrict__ out,
                 const float* __restrict__ v_prev_raw, float scale, int mode, int nch) {
  const int b = blockIdx.x;
  const int t = threadIdx.x;

  float s = 0.f;
  for (int ch = 0; ch < nch; ++ch)
    s += s_part[((size_t)b * nch + ch) * 256 + t];
  s *= scale;

  float sq = s * s;
  sq += __shfl_xor(sq, 1);
  sq += __shfl_xor(sq, 2);
  sq += __shfl_xor(sq, 4);
  sq += __shfl_xor(sq, 8);
  const float f = sq / ((1.f + sq) * sqrtf(sq + 1e-8f));
  const float v = s * f;

  if (mode == 0) {
    vraw[b * 256 + t]    = v;
    vs_next[b * 256 + t] = v * LOG2E_;
  } else if (mode == 1) {
    vs_next[b * 256 + t] = (v + v_prev_raw[b * 256 + t]) * LOG2E_;
  } else {
    out[b * 256 + t] = v;
  }
}

extern "C" void kernel_launch(void* const* d_in, const int* in_sizes, int n_in,
                              void* d_out, int out_size, void* d_ws, size_t ws_size,
                              hipStream_t stream) {
  (void)in_sizes; (void)n_in; (void)out_size;

  const float* x = (const float*)d_in[0];
  const float* W = (const float*)d_in[1];
  float* out = (float*)d_out;

  const size_t vbytes  = (size_t)B_ * NC_ * OD_ * sizeof(float);     // 128 KB
  const size_t need32  = (size_t)B_ * 32 * 256 * sizeof(float) + 2 * vbytes;
  const bool   big     = (ws_size >= need32);
  const int    CHsel   = big ? 32 : 16;

  float* s_part = (float*)d_ws;
  float* v1raw  = s_part + (size_t)B_ * CHsel * 256;
  float* vs     = v1raw + (size_t)B_ * NC_ * OD_;

  const dim3 gridP(B_ / BB_, CHsel), blk(256), gridR(B_);

  if (big) {
    caps_pass<true , 32><<<gridP, blk, 0, stream>>>(x, W, nullptr, s_part);
    caps_reduce<<<gridR, blk, 0, stream>>>(s_part, v1raw, vs, nullptr, nullptr, 1.f/16.f, 0, 32);
    caps_pass<false, 32><<<gridP, blk, 0, stream>>>(x, W, vs, s_part);
    caps_reduce<<<gridR, blk, 0, stream>>>(s_part, nullptr, vs, nullptr, v1raw, 1.f, 1, 32);
    caps_pass<false, 32><<<gridP, blk, 0, stream>>>(x, W, vs, s_part);
    caps_reduce<<<gridR, blk, 0, stream>>>(s_part, nullptr, nullptr, out, nullptr, 1.f, 2, 32);
  } else {
    caps_pass<true , 16><<<gridP, blk, 0, stream>>>(x, W, nullptr, s_part);
    caps_reduce<<<gridR, blk, 0, stream>>>(s_part, v1raw, vs, nullptr, nullptr, 1.f/16.f, 0, 16);
    caps_pass<false, 16><<<gridP, blk, 0, stream>>>(x, W, vs, s_part);
    caps_reduce<<<gridR, blk, 0, stream>>>(s_part, nullptr, vs, nullptr, v1raw, 1.f, 1, 16);
    caps_pass<false, 16><<<gridP, blk, 0, stream>>>(x, W, vs, s_part);
    caps_reduce<<<gridR, blk, 0, stream>>>(s_part, nullptr, nullptr, out, nullptr, 1.f, 2, 16);
  }
}

// Round 3
// 201.182 us; speedup vs baseline: 1.5253x; 1.5253x over previous
//
#include <hip/hip_runtime.h>
#include <math.h>

#define IC_   2048
#define NC_   16
#define OD_   16
#define ID_   8
#define B_    128
#define NW_   4            // waves per block
#define BB_   4            // batch elements per block (W register reuse)
#define LOG2E_ 1.4426950408889634f

__device__ __forceinline__ float4 ld4(const float* p) { return *(const float4*)p; }

__device__ __forceinline__ float dot8(float4 a0, float4 a1, float4 b0, float4 b1) {
  float s = a0.x * b0.x;
  s = fmaf(a0.y, b0.y, s); s = fmaf(a0.z, b0.z, s); s = fmaf(a0.w, b0.w, s);
  s = fmaf(a1.x, b1.x, s); s = fmaf(a1.y, b1.y, s); s = fmaf(a1.z, b1.z, s);
  s = fmaf(a1.w, b1.w, s);
  return s;
}

// add with DPP-moved partner (VALU only, no DS pipe)
template<int CTRL>
__device__ __forceinline__ float dpp_add(float x) {
  const int xi = __builtin_bit_cast(int, x);
  const int yi = __builtin_amdgcn_update_dpp(xi, xi, CTRL, 0xF, 0xF, false);
  return x + __builtin_bit_cast(float, yi);
}
// butterfly sum across each 16-lane row: result in all lanes of the row
__device__ __forceinline__ float row16_sum(float x) {
  x = dpp_add<0x0B1>(x);  // quad_perm [1,0,3,2]  (xor 1)
  x = dpp_add<0x04E>(x);  // quad_perm [2,3,0,1]  (xor 2)
  x = dpp_add<0x141>(x);  // row_half_mirror      (xor 4)
  x = dpp_add<0x140>(x);  // row_mirror           (xor 8)
  return x;
}

// One routing pass. Lane layout (round-1 style, coalesced W):
//   lane l owns co = l + 64k (k=0..3)  ->  o = l&15, c = (l>>4) + 4k.
// W[i] per-lane floats [ (l+64k)*8 , +8 )  -> float4 pairs, 32B lane stride (coalesced).
// W regs reused across BB_ batch elements. Logit reduce over o = row16 DPP sum.
template<bool UNIFORM, int CH>
__global__ __launch_bounds__(256)
void caps_pass(const float* __restrict__ x, const float* __restrict__ W,
               const float* __restrict__ vs, float* __restrict__ s_part) {
  constexpr int ICPB  = IC_ / CH;
  constexpr int TITER = ICPB / NW_;
  const int bg   = blockIdx.x;
  const int ch   = blockIdx.y;
  const int tid  = threadIdx.x;
  const int wid  = tid >> 6;
  const int lane = tid & 63;

  // v (pre-scaled by log2e): vr[bb][k] = vs[b*256 + lane + 64k]
  float4 vr[BB_];
  if (!UNIFORM) {
#pragma unroll
    for (int bb = 0; bb < BB_; ++bb) {
      const float* vp = vs + (size_t)(bg * BB_ + bb) * 256 + lane;
      vr[bb] = make_float4(vp[0], vp[64], vp[128], vp[192]);
    }
  }

  float4 acc[BB_];
#pragma unroll
  for (int bb = 0; bb < BB_; ++bb) acc[bb] = make_float4(0.f, 0.f, 0.f, 0.f);

  for (int t = 0; t < TITER; ++t) {
    const int i = ch * ICPB + t * NW_ + wid;
    const float* wr = W + (size_t)i * (NC_ * OD_ * ID_) + lane * ID_;
    const float4 wa0 = ld4(wr);        const float4 wa1 = ld4(wr + 4);
    const float4 wb0 = ld4(wr + 512);  const float4 wb1 = ld4(wr + 516);
    const float4 wc0 = ld4(wr + 1024); const float4 wc1 = ld4(wr + 1028);
    const float4 wd0 = ld4(wr + 1536); const float4 wd1 = ld4(wr + 1540);

#pragma unroll
    for (int bb = 0; bb < BB_; ++bb) {
      const float* xp = x + ((size_t)(bg * BB_ + bb) * IC_ + i) * ID_;
      const float4 x0 = ld4(xp);
      const float4 x1 = ld4(xp + 4);

      const float u0 = dot8(wa0, wa1, x0, x1);
      const float u1 = dot8(wb0, wb1, x0, x1);
      const float u2 = dot8(wc0, wc1, x0, x1);
      const float u3 = dot8(wd0, wd1, x0, x1);

      if (UNIFORM) {
        acc[bb].x += u0; acc[bb].y += u1; acc[bb].z += u2; acc[bb].w += u3;
      } else {
        // logits per c (reduce u*v over the 16-lane o-row), already scaled by log2e
        const float d0 = row16_sum(u0 * vr[bb].x);
        const float d1 = row16_sum(u1 * vr[bb].y);
        const float d2 = row16_sum(u2 * vr[bb].z);
        const float d3 = row16_sum(u3 * vr[bb].w);
        const float e0 = __builtin_amdgcn_exp2f(d0);
        const float e1 = __builtin_amdgcn_exp2f(d1);
        const float e2 = __builtin_amdgcn_exp2f(d2);
        const float e3 = __builtin_amdgcn_exp2f(d3);
        float Z = (e0 + e1) + (e2 + e3);     // sum over c within this row-group
        Z += __shfl_xor(Z, 16);              // combine the 4 row-groups
        Z += __shfl_xor(Z, 32);
        const float r = __builtin_amdgcn_rcpf(Z);
        acc[bb].x = fmaf(e0 * r, u0, acc[bb].x);
        acc[bb].y = fmaf(e1 * r, u1, acc[bb].y);
        acc[bb].z = fmaf(e2 * r, u2, acc[bb].z);
        acc[bb].w = fmaf(e3 * r, u3, acc[bb].w);
      }
    }
  }

  // cross-wave reduce: consecutive-lane scalar writes/reads, conflict-free
  __shared__ float red[NW_][BB_ * 256];
#pragma unroll
  for (int bb = 0; bb < BB_; ++bb) {
    red[wid][bb * 256 + lane]       = acc[bb].x;
    red[wid][bb * 256 + lane + 64]  = acc[bb].y;
    red[wid][bb * 256 + lane + 128] = acc[bb].z;
    red[wid][bb * 256 + lane + 192] = acc[bb].w;
  }
  __syncthreads();
#pragma unroll
  for (int bb = 0; bb < BB_; ++bb) {
    const int idx = bb * 256 + tid;
    const float s = red[0][idx] + red[1][idx] + red[2][idx] + red[3][idx];
    s_part[((size_t)(bg * BB_ + bb) * CH + ch) * 256 + tid] = s;
  }
}

// Reduce partials over nch chunks, squash, produce v / scaled-v / output.
// mode 0: vraw = v1, vs_next = v1*log2e            (scale = 1/16)
// mode 1: vs_next = (v1raw + v2)*log2e             (scale = 1)
// mode 2: out = v3                                 (scale = 1)
__global__ __launch_bounds__(256)
void caps_reduce(const float* __restrict__ s_part, float* __restrict__ vraw,
                 float* __restrict__ vs_next, float* __restrict__ out,
                 const float* __restrict__ v_prev_raw, float scale, int mode, int nch) {
  const int b = blockIdx.x;
  const int t = threadIdx.x;

  float s = 0.f;
  for (int ch = 0; ch < nch; ++ch)
    s += s_part[((size_t)b * nch + ch) * 256 + t];
  s *= scale;

  float sq = s * s;
  sq += __shfl_xor(sq, 1);
  sq += __shfl_xor(sq, 2);
  sq += __shfl_xor(sq, 4);
  sq += __shfl_xor(sq, 8);
  const float f = sq / ((1.f + sq) * sqrtf(sq + 1e-8f));
  const float v = s * f;

  if (mode == 0) {
    vraw[b * 256 + t]    = v;
    vs_next[b * 256 + t] = v * LOG2E_;
  } else if (mode == 1) {
    vs_next[b * 256 + t] = (v + v_prev_raw[b * 256 + t]) * LOG2E_;
  } else {
    out[b * 256 + t] = v;
  }
}

extern "C" void kernel_launch(void* const* d_in, const int* in_sizes, int n_in,
                              void* d_out, int out_size, void* d_ws, size_t ws_size,
                              hipStream_t stream) {
  (void)in_sizes; (void)n_in; (void)out_size;

  const float* x = (const float*)d_in[0];
  const float* W = (const float*)d_in[1];
  float* out = (float*)d_out;

  const size_t vbytes = (size_t)B_ * NC_ * OD_ * sizeof(float);       // 128 KB
  const size_t need64 = (size_t)B_ * 64 * 256 * sizeof(float) + 2 * vbytes;
  const bool   big    = (ws_size >= need64);
  const int    CHsel  = big ? 64 : 32;

  float* s_part = (float*)d_ws;
  float* v1raw  = s_part + (size_t)B_ * CHsel * 256;
  float* vs     = v1raw + (size_t)B_ * NC_ * OD_;

  const dim3 gridP(B_ / BB_, CHsel), blk(256), gridR(B_);

  if (big) {
    caps_pass<true , 64><<<gridP, blk, 0, stream>>>(x, W, nullptr, s_part);
    caps_reduce<<<gridR, blk, 0, stream>>>(s_part, v1raw, vs, nullptr, nullptr, 1.f/16.f, 0, 64);
    caps_pass<false, 64><<<gridP, blk, 0, stream>>>(x, W, vs, s_part);
    caps_reduce<<<gridR, blk, 0, stream>>>(s_part, nullptr, vs, nullptr, v1raw, 1.f, 1, 64);
    caps_pass<false, 64><<<gridP, blk, 0, stream>>>(x, W, vs, s_part);
    caps_reduce<<<gridR, blk, 0, stream>>>(s_part, nullptr, nullptr, out, nullptr, 1.f, 2, 64);
  } else {
    caps_pass<true , 32><<<gridP, blk, 0, stream>>>(x, W, nullptr, s_part);
    caps_reduce<<<gridR, blk, 0, stream>>>(s_part, v1raw, vs, nullptr, nullptr, 1.f/16.f, 0, 32);
    caps_pass<false, 32><<<gridP, blk, 0, stream>>>(x, W, vs, s_part);
    caps_reduce<<<gridR, blk, 0, stream>>>(s_part, nullptr, vs, nullptr, v1raw, 1.f, 1, 32);
    caps_pass<false, 32><<<gridP, blk, 0, stream>>>(x, W, vs, s_part);
    caps_reduce<<<gridR, blk, 0, stream>>>(s_part, nullptr, nullptr, out, nullptr, 1.f, 2, 32);
  }
}

// Round 4
// 177.371 us; speedup vs baseline: 1.7300x; 1.1342x over previous
//
#include <hip/hip_runtime.h>
#include <math.h>

#define IC_   2048
#define NC_   16
#define OD_   16
#define ID_   8
#define B_    128
#define NW_   4            // waves per block
#define BB_   4            // batch elements per block (W register reuse)
#define LOG2E_ 1.4426950408889634f

typedef _Float16 h2 __attribute__((ext_vector_type(2)));
typedef _Float16 h8 __attribute__((ext_vector_type(8)));

__device__ __forceinline__ float4 ld4(const float* p) { return *(const float4*)p; }

// add with DPP-moved partner (VALU only, no DS pipe)
template<int CTRL>
__device__ __forceinline__ float dpp_add(float x) {
  const int xi = __builtin_bit_cast(int, x);
  const int yi = __builtin_amdgcn_update_dpp(xi, xi, CTRL, 0xF, 0xF, false);
  return x + __builtin_bit_cast(float, yi);
}
// butterfly sum across each 16-lane row: result in all lanes of the row
__device__ __forceinline__ float row16_sum(float x) {
  x = dpp_add<0x0B1>(x);  // quad_perm [1,0,3,2]  (xor 1)
  x = dpp_add<0x04E>(x);  // quad_perm [2,3,0,1]  (xor 2)
  x = dpp_add<0x141>(x);  // row_half_mirror      (xor 4)
  x = dpp_add<0x140>(x);  // row_mirror           (xor 8)
  return x;
}

__device__ __forceinline__ float dot8f(float4 a0, float4 a1, float4 b0, float4 b1) {
  float s = a0.x * b0.x;
  s = fmaf(a0.y, b0.y, s); s = fmaf(a0.z, b0.z, s); s = fmaf(a0.w, b0.w, s);
  s = fmaf(a1.x, b1.x, s); s = fmaf(a1.y, b1.y, s); s = fmaf(a1.z, b1.z, s);
  s = fmaf(a1.w, b1.w, s);
  return s;
}

__device__ __forceinline__ float dot8h(h8 w, h8 x) {
  const h2 w0 = __builtin_shufflevector(w, w, 0, 1), x0 = __builtin_shufflevector(x, x, 0, 1);
  const h2 w1 = __builtin_shufflevector(w, w, 2, 3), x1 = __builtin_shufflevector(x, x, 2, 3);
  const h2 w2 = __builtin_shufflevector(w, w, 4, 5), x2 = __builtin_shufflevector(x, x, 4, 5);
  const h2 w3 = __builtin_shufflevector(w, w, 6, 7), x3 = __builtin_shufflevector(x, x, 6, 7);
  float s = __builtin_amdgcn_fdot2(w0, x0, 0.f, false);
  s = __builtin_amdgcn_fdot2(w1, x1, s, false);
  s = __builtin_amdgcn_fdot2(w2, x2, s, false);
  s = __builtin_amdgcn_fdot2(w3, x3, s, false);
  return s;
}

// fp32 -> fp16 conversion, 8 elements/thread
__global__ __launch_bounds__(256)
void cvt16(const float* __restrict__ in, _Float16* __restrict__ out, int n8) {
  for (int idx = blockIdx.x * 256 + threadIdx.x; idx < n8; idx += gridDim.x * 256) {
    const float4 a = ((const float4*)in)[2 * idx];
    const float4 b = ((const float4*)in)[2 * idx + 1];
    h8 h;
    h[0] = (_Float16)a.x; h[1] = (_Float16)a.y; h[2] = (_Float16)a.z; h[3] = (_Float16)a.w;
    h[4] = (_Float16)b.x; h[5] = (_Float16)b.y; h[6] = (_Float16)b.z; h[7] = (_Float16)b.w;
    ((h8*)out)[idx] = h;
  }
}

// ---------- fp16-input routing pass (fdot2). Lane layout: co = lane + 64k. ----------
template<bool UNIFORM, int CH>
__global__ __launch_bounds__(256)
void caps_pass_h(const _Float16* __restrict__ xh, const _Float16* __restrict__ Wh,
                 const float* __restrict__ vs, float* __restrict__ s_part) {
  constexpr int ICPB  = IC_ / CH;
  constexpr int TITER = ICPB / NW_;
  const int bg   = blockIdx.x;
  const int ch   = blockIdx.y;
  const int tid  = threadIdx.x;
  const int wid  = tid >> 6;
  const int lane = tid & 63;

  float4 vr[BB_];
  if (!UNIFORM) {
#pragma unroll
    for (int bb = 0; bb < BB_; ++bb) {
      const float* vp = vs + (size_t)(bg * BB_ + bb) * 256 + lane;
      vr[bb] = make_float4(vp[0], vp[64], vp[128], vp[192]);
    }
  }

  float4 acc[BB_];
#pragma unroll
  for (int bb = 0; bb < BB_; ++bb) acc[bb] = make_float4(0.f, 0.f, 0.f, 0.f);

  for (int t = 0; t < TITER; ++t) {
    const int i = ch * ICPB + t * NW_ + wid;
    const _Float16* wr = Wh + (size_t)i * (NC_ * OD_ * ID_) + lane * ID_;
    const h8 wa = *(const h8*)(wr);
    const h8 wb = *(const h8*)(wr + 512);
    const h8 wc = *(const h8*)(wr + 1024);
    const h8 wd = *(const h8*)(wr + 1536);

#pragma unroll
    for (int bb = 0; bb < BB_; ++bb) {
      const h8 xv = *(const h8*)(xh + ((size_t)(bg * BB_ + bb) * IC_ + i) * ID_);

      const float u0 = dot8h(wa, xv);
      const float u1 = dot8h(wb, xv);
      const float u2 = dot8h(wc, xv);
      const float u3 = dot8h(wd, xv);

      if (UNIFORM) {
        acc[bb].x += u0; acc[bb].y += u1; acc[bb].z += u2; acc[bb].w += u3;
      } else {
        const float d0 = row16_sum(u0 * vr[bb].x);
        const float d1 = row16_sum(u1 * vr[bb].y);
        const float d2 = row16_sum(u2 * vr[bb].z);
        const float d3 = row16_sum(u3 * vr[bb].w);
        const float e0 = __builtin_amdgcn_exp2f(d0);
        const float e1 = __builtin_amdgcn_exp2f(d1);
        const float e2 = __builtin_amdgcn_exp2f(d2);
        const float e3 = __builtin_amdgcn_exp2f(d3);
        float Z = (e0 + e1) + (e2 + e3);
        Z += __shfl_xor(Z, 16);
        Z += __shfl_xor(Z, 32);
        const float r = __builtin_amdgcn_rcpf(Z);
        acc[bb].x = fmaf(e0 * r, u0, acc[bb].x);
        acc[bb].y = fmaf(e1 * r, u1, acc[bb].y);
        acc[bb].z = fmaf(e2 * r, u2, acc[bb].z);
        acc[bb].w = fmaf(e3 * r, u3, acc[bb].w);
      }
    }
  }

  __shared__ float red[NW_][BB_ * 256];
#pragma unroll
  for (int bb = 0; bb < BB_; ++bb) {
    red[wid][bb * 256 + lane]       = acc[bb].x;
    red[wid][bb * 256 + lane + 64]  = acc[bb].y;
    red[wid][bb * 256 + lane + 128] = acc[bb].z;
    red[wid][bb * 256 + lane + 192] = acc[bb].w;
  }
  __syncthreads();
#pragma unroll
  for (int bb = 0; bb < BB_; ++bb) {
    const int idx = bb * 256 + tid;
    const float s = red[0][idx] + red[1][idx] + red[2][idx] + red[3][idx];
    s_part[((size_t)(bg * BB_ + bb) * CH + ch) * 256 + tid] = s;
  }
}

// ---------- fp32 fallback pass (round-3 proven) ----------
template<bool UNIFORM, int CH>
__global__ __launch_bounds__(256)
void caps_pass_f32(const float* __restrict__ x, const float* __restrict__ W,
                   const float* __restrict__ vs, float* __restrict__ s_part) {
  constexpr int ICPB  = IC_ / CH;
  constexpr int TITER = ICPB / NW_;
  const int bg   = blockIdx.x;
  const int ch   = blockIdx.y;
  const int tid  = threadIdx.x;
  const int wid  = tid >> 6;
  const int lane = tid & 63;

  float4 vr[BB_];
  if (!UNIFORM) {
#pragma unroll
    for (int bb = 0; bb < BB_; ++bb) {
      const float* vp = vs + (size_t)(bg * BB_ + bb) * 256 + lane;
      vr[bb] = make_float4(vp[0], vp[64], vp[128], vp[192]);
    }
  }

  float4 acc[BB_];
#pragma unroll
  for (int bb = 0; bb < BB_; ++bb) acc[bb] = make_float4(0.f, 0.f, 0.f, 0.f);

  for (int t = 0; t < TITER; ++t) {
    const int i = ch * ICPB + t * NW_ + wid;
    const float* wr = W + (size_t)i * (NC_ * OD_ * ID_) + lane * ID_;
    const float4 wa0 = ld4(wr);        const float4 wa1 = ld4(wr + 4);
    const float4 wb0 = ld4(wr + 512);  const float4 wb1 = ld4(wr + 516);
    const float4 wc0 = ld4(wr + 1024); const float4 wc1 = ld4(wr + 1028);
    const float4 wd0 = ld4(wr + 1536); const float4 wd1 = ld4(wr + 1540);

#pragma unroll
    for (int bb = 0; bb < BB_; ++bb) {
      const float* xp = x + ((size_t)(bg * BB_ + bb) * IC_ + i) * ID_;
      const float4 x0 = ld4(xp);
      const float4 x1 = ld4(xp + 4);

      const float u0 = dot8f(wa0, wa1, x0, x1);
      const float u1 = dot8f(wb0, wb1, x0, x1);
      const float u2 = dot8f(wc0, wc1, x0, x1);
      const float u3 = dot8f(wd0, wd1, x0, x1);

      if (UNIFORM) {
        acc[bb].x += u0; acc[bb].y += u1; acc[bb].z += u2; acc[bb].w += u3;
      } else {
        const float d0 = row16_sum(u0 * vr[bb].x);
        const float d1 = row16_sum(u1 * vr[bb].y);
        const float d2 = row16_sum(u2 * vr[bb].z);
        const float d3 = row16_sum(u3 * vr[bb].w);
        const float e0 = __builtin_amdgcn_exp2f(d0);
        const float e1 = __builtin_amdgcn_exp2f(d1);
        const float e2 = __builtin_amdgcn_exp2f(d2);
        const float e3 = __builtin_amdgcn_exp2f(d3);
        float Z = (e0 + e1) + (e2 + e3);
        Z += __shfl_xor(Z, 16);
        Z += __shfl_xor(Z, 32);
        const float r = __builtin_amdgcn_rcpf(Z);
        acc[bb].x = fmaf(e0 * r, u0, acc[bb].x);
        acc[bb].y = fmaf(e1 * r, u1, acc[bb].y);
        acc[bb].z = fmaf(e2 * r, u2, acc[bb].z);
        acc[bb].w = fmaf(e3 * r, u3, acc[bb].w);
      }
    }
  }

  __shared__ float red[NW_][BB_ * 256];
#pragma unroll
  for (int bb = 0; bb < BB_; ++bb) {
    red[wid][bb * 256 + lane]       = acc[bb].x;
    red[wid][bb * 256 + lane + 64]  = acc[bb].y;
    red[wid][bb * 256 + lane + 128] = acc[bb].z;
    red[wid][bb * 256 + lane + 192] = acc[bb].w;
  }
  __syncthreads();
#pragma unroll
  for (int bb = 0; bb < BB_; ++bb) {
    const int idx = bb * 256 + tid;
    const float s = red[0][idx] + red[1][idx] + red[2][idx] + red[3][idx];
    s_part[((size_t)(bg * BB_ + bb) * CH + ch) * 256 + tid] = s;
  }
}

// Reduce partials over nch chunks, squash, produce v / scaled-v / output.
// mode 0: vraw = v1, vs_next = v1*log2e            (scale = 1/16)
// mode 1: vs_next = (v1raw + v2)*log2e             (scale = 1)
// mode 2: out = v3                                 (scale = 1)
__global__ __launch_bounds__(256)
void caps_reduce(const float* __restrict__ s_part, float* __restrict__ vraw,
                 float* __restrict__ vs_next, float* __restrict__ out,
                 const float* __restrict__ v_prev_raw, float scale, int mode, int nch) {
  const int b = blockIdx.x;
  const int t = threadIdx.x;

  float s = 0.f;
  for (int ch = 0; ch < nch; ++ch)
    s += s_part[((size_t)b * nch + ch) * 256 + t];
  s *= scale;

  float sq = s * s;
  sq += __shfl_xor(sq, 1);
  sq += __shfl_xor(sq, 2);
  sq += __shfl_xor(sq, 4);
  sq += __shfl_xor(sq, 8);
  const float f = sq / ((1.f + sq) * sqrtf(sq + 1e-8f));
  const float v = s * f;

  if (mode == 0) {
    vraw[b * 256 + t]    = v;
    vs_next[b * 256 + t] = v * LOG2E_;
  } else if (mode == 1) {
    vs_next[b * 256 + t] = (v + v_prev_raw[b * 256 + t]) * LOG2E_;
  } else {
    out[b * 256 + t] = v;
  }
}

extern "C" void kernel_launch(void* const* d_in, const int* in_sizes, int n_in,
                              void* d_out, int out_size, void* d_ws, size_t ws_size,
                              hipStream_t stream) {
  (void)in_sizes; (void)n_in; (void)out_size;

  const float* x = (const float*)d_in[0];
  const float* W = (const float*)d_in[1];
  float* out = (float*)d_out;

  const size_t nW = (size_t)IC_ * NC_ * OD_ * ID_;   // 4 Mi elements
  const size_t nX = (size_t)B_ * IC_ * ID_;          // 2 Mi elements
  const size_t vbytes = (size_t)B_ * NC_ * OD_ * sizeof(float);   // 128 KB

  auto spart_bytes = [&](int ch) { return (size_t)B_ * ch * 256 * sizeof(float); };
  const size_t cvt_bytes = (nW + nX) * sizeof(_Float16);          // 12 MB

  const dim3 blk(256), gridR(B_);

  // tier selection by ws_size
  if (ws_size >= spart_bytes(64) + 2 * vbytes + cvt_bytes) {
    constexpr int CH = 64;
    float* s_part = (float*)d_ws;
    float* v1raw  = s_part + (size_t)B_ * CH * 256;
    float* vs     = v1raw + (size_t)B_ * NC_ * OD_;
    _Float16* Wh  = (_Float16*)(vs + (size_t)B_ * NC_ * OD_);
    _Float16* xh  = Wh + nW;

    cvt16<<<2048, blk, 0, stream>>>(W, Wh, (int)(nW / 8));
    cvt16<<<1024, blk, 0, stream>>>(x, xh, (int)(nX / 8));

    const dim3 gridP(B_ / BB_, CH);
    caps_pass_h<true , CH><<<gridP, blk, 0, stream>>>(xh, Wh, nullptr, s_part);
    caps_reduce<<<gridR, blk, 0, stream>>>(s_part, v1raw, vs, nullptr, nullptr, 1.f/16.f, 0, CH);
    caps_pass_h<false, CH><<<gridP, blk, 0, stream>>>(xh, Wh, vs, s_part);
    caps_reduce<<<gridR, blk, 0, stream>>>(s_part, nullptr, vs, nullptr, v1raw, 1.f, 1, CH);
    caps_pass_h<false, CH><<<gridP, blk, 0, stream>>>(xh, Wh, vs, s_part);
    caps_reduce<<<gridR, blk, 0, stream>>>(s_part, nullptr, nullptr, out, nullptr, 1.f, 2, CH);
  } else if (ws_size >= spart_bytes(32) + 2 * vbytes + cvt_bytes) {
    constexpr int CH = 32;
    float* s_part = (float*)d_ws;
    float* v1raw  = s_part + (size_t)B_ * CH * 256;
    float* vs     = v1raw + (size_t)B_ * NC_ * OD_;
    _Float16* Wh  = (_Float16*)(vs + (size_t)B_ * NC_ * OD_);
    _Float16* xh  = Wh + nW;

    cvt16<<<2048, blk, 0, stream>>>(W, Wh, (int)(nW / 8));
    cvt16<<<1024, blk, 0, stream>>>(x, xh, (int)(nX / 8));

    const dim3 gridP(B_ / BB_, CH);
    caps_pass_h<true , CH><<<gridP, blk, 0, stream>>>(xh, Wh, nullptr, s_part);
    caps_reduce<<<gridR, blk, 0, stream>>>(s_part, v1raw, vs, nullptr, nullptr, 1.f/16.f, 0, CH);
    caps_pass_h<false, CH><<<gridP, blk, 0, stream>>>(xh, Wh, vs, s_part);
    caps_reduce<<<gridR, blk, 0, stream>>>(s_part, nullptr, vs, nullptr, v1raw, 1.f, 1, CH);
    caps_pass_h<false, CH><<<gridP, blk, 0, stream>>>(xh, Wh, vs, s_part);
    caps_reduce<<<gridR, blk, 0, stream>>>(s_part, nullptr, nullptr, out, nullptr, 1.f, 2, CH);
  } else if (ws_size >= spart_bytes(64) + 2 * vbytes) {
    constexpr int CH = 64;
    float* s_part = (float*)d_ws;
    float* v1raw  = s_part + (size_t)B_ * CH * 256;
    float* vs     = v1raw + (size_t)B_ * NC_ * OD_;

    const dim3 gridP(B_ / BB_, CH);
    caps_pass_f32<true , CH><<<gridP, blk, 0, stream>>>(x, W, nullptr, s_part);
    caps_reduce<<<gridR, blk, 0, stream>>>(s_part, v1raw, vs, nullptr, nullptr, 1.f/16.f, 0, CH);
    caps_pass_f32<false, CH><<<gridP, blk, 0, stream>>>(x, W, vs, s_part);
    caps_reduce<<<gridR, blk, 0, stream>>>(s_part, nullptr, vs, nullptr, v1raw, 1.f, 1, CH);
    caps_pass_f32<false, CH><<<gridP, blk, 0, stream>>>(x, W, vs, s_part);
    caps_reduce<<<gridR, blk, 0, stream>>>(s_part, nullptr, nullptr, out, nullptr, 1.f, 2, CH);
  } else {
    constexpr int CH = 32;
    float* s_part = (float*)d_ws;
    float* v1raw  = s_part + (size_t)B_ * CH * 256;
    float* vs     = v1raw + (size_t)B_ * NC_ * OD_;

    const dim3 gridP(B_ / BB_, CH);
    caps_pass_f32<true , CH><<<gridP, blk, 0, stream>>>(x, W, nullptr, s_part);
    caps_reduce<<<gridR, blk, 0, stream>>>(s_part, v1raw, vs, nullptr, nullptr, 1.f/16.f, 0, CH);
    caps_pass_f32<false, CH><<<gridP, blk, 0, stream>>>(x, W, vs, s_part);
    caps_reduce<<<gridR, blk, 0, stream>>>(s_part, nullptr, vs, nullptr, v1raw, 1.f, 1, CH);
    caps_pass_f32<false, CH><<<gridP, blk, 0, stream>>>(x, W, vs, s_part);
    caps_reduce<<<gridR, blk, 0, stream>>>(s_part, nullptr, nullptr, out, nullptr, 1.f, 2, CH);
  }
}

// Round 5
// 162.196 us; speedup vs baseline: 1.8919x; 1.0936x over previous
//
#include <hip/hip_runtime.h>
#include <math.h>

#define IC_   2048
#define NC_   16
#define OD_   16
#define ID_   8
#define B_    128
#define LOG2E_ 1.4426950408889634f

typedef _Float16 h2 __attribute__((ext_vector_type(2)));
typedef _Float16 h4 __attribute__((ext_vector_type(4)));
typedef _Float16 h8 __attribute__((ext_vector_type(8)));
typedef float    f4 __attribute__((ext_vector_type(4)));

// ---------------- fp32 -> fp16 flat conversion (8 elems/thread) ----------------
__global__ __launch_bounds__(256)
void cvt16(const float* __restrict__ in, _Float16* __restrict__ out, int n8) {
  for (int idx = blockIdx.x * 256 + threadIdx.x; idx < n8; idx += gridDim.x * 256) {
    const float4 a = ((const float4*)in)[2 * idx];
    const float4 b = ((const float4*)in)[2 * idx + 1];
    h8 h;
    h[0] = (_Float16)a.x; h[1] = (_Float16)a.y; h[2] = (_Float16)a.z; h[3] = (_Float16)a.w;
    h[4] = (_Float16)b.x; h[5] = (_Float16)b.y; h[6] = (_Float16)b.z; h[7] = (_Float16)b.w;
    ((h8*)out)[idx] = h;
  }
}

// ---------------- MFMA routing pass ----------------
// Grid: (64 i-chunks, 8 b-tiles). Block: 4 waves, all on the SAME b-tile;
// wave w handles i in [chunk*32 + w*8, +8).
// MFMA v_mfma_f32_16x16x16f16 per c-tile: A = W[i,c] (M=o rows=lane&15,
// k=d=(lane>>4)*4+j, lanes>=32 zero), B = x (K=d, N=b cols=lane&15),
// D: col=lane&15=b, row=(lane>>4)*4+reg=o.   [K=8 zero-padded to 16]
// Softmax per (b,i): logits p[c] = dot4(u[c], v[c]) + xor16 + xor32; Z in-reg.
// s accumulates in 64 VGPRs; 4-wave LDS reduce -> fp16-packed s_part.
template<bool UNIFORM>
__global__ __launch_bounds__(256, 2)
void caps_mfma(const _Float16* __restrict__ xh, const _Float16* __restrict__ Wh,
               const float* __restrict__ vs, unsigned int* __restrict__ s_part) {
  const int chunk = blockIdx.x;
  const int bt    = blockIdx.y;
  const int tid   = threadIdx.x;
  const int wid   = tid >> 6;
  const int lane  = tid & 63;
  const int m     = lane & 15;        // A-row(o) / B-col(b) / D-col(b)
  const int g4    = lane >> 4;        // 0..3: D row-group / K-block
  const bool lo   = lane < 32;        // K<8 lanes (softmax passes)
  const int i0    = chunk * 32 + wid * 8;

  f4 sreg[16];
#pragma unroll
  for (int c = 0; c < 16; ++c) sreg[c] = (f4)0.f;

  f4 vv[16];
  if (!UNIFORM) {
    const float* vb = vs + (size_t)(bt * 16 + m) * 256 + g4 * 4;
#pragma unroll
    for (int c = 0; c < 16; ++c) vv[c] = *(const f4*)(vb + c * 16);
  }

  if (UNIFORM) {
    // pack 2 i's into K=16: k-blocks 0,1 -> i, k-blocks 2,3 -> i+1 (sum over i is wanted)
    const int ieo = g4 >> 1;       // which i of the pair this lane's k-block covers
    const int gk2 = g4 & 1;        // k-subblock within that i
    for (int it = 0; it < 4; ++it) {
      const int i = i0 + it * 2 + ieo;
      const h4 xb = *(const h4*)(xh + ((size_t)(bt * 16 + m) * IC_ + i) * ID_ + gk2 * 4);
      const _Float16* wbase = Wh + ((size_t)i * 256 + m) * ID_ + gk2 * 4;
#pragma unroll
      for (int c = 0; c < 16; ++c) {
        const h4 a = *(const h4*)(wbase + c * (16 * ID_));
        sreg[c] = __builtin_amdgcn_mfma_f32_16x16x16f16(a, xb, sreg[c], 0, 0, 0);
      }
    }
  } else {
    const int gk = g4 & 1;
    for (int it = 0; it < 8; ++it) {
      const int i = i0 + it;
      h4 xb{};
      if (lo) xb = *(const h4*)(xh + ((size_t)(bt * 16 + m) * IC_ + i) * ID_ + gk * 4);
      const _Float16* wbase = Wh + ((size_t)i * 256 + m) * ID_ + gk * 4;

      f4 u[16];
#pragma unroll
      for (int c = 0; c < 16; ++c) {
        h4 a{};
        if (lo) a = *(const h4*)(wbase + c * (16 * ID_));
        u[c] = __builtin_amdgcn_mfma_f32_16x16x16f16(a, xb, (f4)0.f, 0, 0, 0);
      }

      float p[16];
#pragma unroll
      for (int c = 0; c < 16; ++c) {
        float d = u[c][0] * vv[c][0];
        d = fmaf(u[c][1], vv[c][1], d);
        d = fmaf(u[c][2], vv[c][2], d);
        d = fmaf(u[c][3], vv[c][3], d);
        p[c] = d;
      }
#pragma unroll
      for (int c = 0; c < 16; ++c) {
        p[c] += __shfl_xor(p[c], 16);
        p[c] += __shfl_xor(p[c], 32);
        p[c] = __builtin_amdgcn_exp2f(p[c]);   // vs pre-scaled by log2e; |logit| tiny
      }
      float Z = 0.f;
#pragma unroll
      for (int c = 0; c < 16; ++c) Z += p[c];
      const float r = __builtin_amdgcn_rcpf(Z);
#pragma unroll
      for (int c = 0; c < 16; ++c) {
        const float w = p[c] * r;
        sreg[c][0] = fmaf(w, u[c][0], sreg[c][0]);
        sreg[c][1] = fmaf(w, u[c][1], sreg[c][1]);
        sreg[c][2] = fmaf(w, u[c][2], sreg[c][2]);
        sreg[c][3] = fmaf(w, u[c][3], sreg[c][3]);
      }
    }
  }

  // 4-wave LDS reduce, then fp16-pack and store 2048 dwords per block.
  __shared__ f4 red[4][16 * 64];          // 64 KB
#pragma unroll
  for (int c = 0; c < 16; ++c) red[wid][c * 64 + lane] = sreg[c];
  __syncthreads();

  const float* rf = (const float*)&red[0][0];   // flat idx f = w*4096 + (c*64+l)*4 + r
  unsigned int* dst = s_part + (size_t)(chunk * 8 + bt) * 2048;
#pragma unroll
  for (int j = 0; j < 8; ++j) {
    const int dwidx = j * 256 + tid;
    const int f0 = 2 * dwidx;
    const float s0 = rf[f0]     + rf[4096 + f0]     + rf[8192 + f0]     + rf[12288 + f0];
    const float s1 = rf[f0 + 1] + rf[4096 + f0 + 1] + rf[8192 + f0 + 1] + rf[12288 + f0 + 1];
    h2 hv; hv[0] = (_Float16)s0; hv[1] = (_Float16)s1;
    dst[dwidx] = __builtin_bit_cast(unsigned int, hv);
  }
}

// ---------------- reduce over 64 chunks + squash (MFMA-path layout) ----------------
// mode 0: vraw=v1, vs_next=v1*log2e (scale=1/16); mode 1: vs_next=(v1raw+v2)*log2e;
// mode 2: out=v3.
__global__ __launch_bounds__(256)
void caps_reduce2(const unsigned int* __restrict__ sp, float* __restrict__ vraw,
                  float* __restrict__ vs_next, float* __restrict__ out,
                  const float* __restrict__ v_prev_raw, float scale, int mode) {
  const int b = blockIdx.x;
  const int t = threadIdx.x;          // t = co = c*16 + o
  const int c = t >> 4, o = t & 15;
  const int r = o & 3, g = o >> 2;
  const int l = g * 16 + (b & 15);
  const int f = (c * 64 + l) * 4 + r;
  const int dwidx = f >> 1, hi = f & 1;
  const int bt = b >> 4;

  float s = 0.f;
  for (int ch = 0; ch < 64; ++ch) {
    const unsigned int dw = sp[(size_t)(ch * 8 + bt) * 2048 + dwidx];
    const h2 hv = __builtin_bit_cast(h2, dw);
    s += (float)(hi ? hv[1] : hv[0]);
  }
  s *= scale;

  float sq = s * s;
  sq += __shfl_xor(sq, 1);
  sq += __shfl_xor(sq, 2);
  sq += __shfl_xor(sq, 4);
  sq += __shfl_xor(sq, 8);
  const float fq = sq / ((1.f + sq) * sqrtf(sq + 1e-8f));
  const float v = s * fq;

  if (mode == 0) {
    vraw[b * 256 + t]    = v;
    vs_next[b * 256 + t] = v * LOG2E_;
  } else if (mode == 1) {
    vs_next[b * 256 + t] = (v + v_prev_raw[b * 256 + t]) * LOG2E_;
  } else {
    out[b * 256 + t] = v;
  }
}

// ================= fp32 fallback (round-3 proven) =================
__device__ __forceinline__ float4 ld4(const float* p) { return *(const float4*)p; }
__device__ __forceinline__ float dot8f(float4 a0, float4 a1, float4 b0, float4 b1) {
  float s = a0.x * b0.x;
  s = fmaf(a0.y, b0.y, s); s = fmaf(a0.z, b0.z, s); s = fmaf(a0.w, b0.w, s);
  s = fmaf(a1.x, b1.x, s); s = fmaf(a1.y, b1.y, s); s = fmaf(a1.z, b1.z, s);
  s = fmaf(a1.w, b1.w, s);
  return s;
}
template<int CTRL>
__device__ __forceinline__ float dpp_add(float x) {
  const int xi = __builtin_bit_cast(int, x);
  const int yi = __builtin_amdgcn_update_dpp(xi, xi, CTRL, 0xF, 0xF, false);
  return x + __builtin_bit_cast(float, yi);
}
__device__ __forceinline__ float row16_sum(float x) {
  x = dpp_add<0x0B1>(x); x = dpp_add<0x04E>(x);
  x = dpp_add<0x141>(x); x = dpp_add<0x140>(x);
  return x;
}
template<bool UNIFORM, int CH>
__global__ __launch_bounds__(256)
void caps_pass_f32(const float* __restrict__ x, const float* __restrict__ W,
                   const float* __restrict__ vs, float* __restrict__ s_part) {
  constexpr int ICPB  = IC_ / CH;
  constexpr int TITER = ICPB / 4;
  const int bg = blockIdx.x, ch = blockIdx.y, tid = threadIdx.x;
  const int wid = tid >> 6, lane = tid & 63;
  float4 vr[4];
  if (!UNIFORM) {
#pragma unroll
    for (int bb = 0; bb < 4; ++bb) {
      const float* vp = vs + (size_t)(bg * 4 + bb) * 256 + lane;
      vr[bb] = make_float4(vp[0], vp[64], vp[128], vp[192]);
    }
  }
  float4 acc[4];
#pragma unroll
  for (int bb = 0; bb < 4; ++bb) acc[bb] = make_float4(0.f, 0.f, 0.f, 0.f);
  for (int t = 0; t < TITER; ++t) {
    const int i = ch * ICPB + t * 4 + wid;
    const float* wr = W + (size_t)i * 2048 + lane * 8;
    const float4 wa0 = ld4(wr);        const float4 wa1 = ld4(wr + 4);
    const float4 wb0 = ld4(wr + 512);  const float4 wb1 = ld4(wr + 516);
    const float4 wc0 = ld4(wr + 1024); const float4 wc1 = ld4(wr + 1028);
    const float4 wd0 = ld4(wr + 1536); const float4 wd1 = ld4(wr + 1540);
#pragma unroll
    for (int bb = 0; bb < 4; ++bb) {
      const float* xp = x + ((size_t)(bg * 4 + bb) * IC_ + i) * ID_;
      const float4 x0 = ld4(xp), x1 = ld4(xp + 4);
      const float u0 = dot8f(wa0, wa1, x0, x1);
      const float u1 = dot8f(wb0, wb1, x0, x1);
      const float u2 = dot8f(wc0, wc1, x0, x1);
      const float u3 = dot8f(wd0, wd1, x0, x1);
      if (UNIFORM) {
        acc[bb].x += u0; acc[bb].y += u1; acc[bb].z += u2; acc[bb].w += u3;
      } else {
        const float d0 = row16_sum(u0 * vr[bb].x);
        const float d1 = row16_sum(u1 * vr[bb].y);
        const float d2 = row16_sum(u2 * vr[bb].z);
        const float d3 = row16_sum(u3 * vr[bb].w);
        const float e0 = __builtin_amdgcn_exp2f(d0);
        const float e1 = __builtin_amdgcn_exp2f(d1);
        const float e2 = __builtin_amdgcn_exp2f(d2);
        const float e3 = __builtin_amdgcn_exp2f(d3);
        float Z = (e0 + e1) + (e2 + e3);
        Z += __shfl_xor(Z, 16); Z += __shfl_xor(Z, 32);
        const float rr = __builtin_amdgcn_rcpf(Z);
        acc[bb].x = fmaf(e0 * rr, u0, acc[bb].x);
        acc[bb].y = fmaf(e1 * rr, u1, acc[bb].y);
        acc[bb].z = fmaf(e2 * rr, u2, acc[bb].z);
        acc[bb].w = fmaf(e3 * rr, u3, acc[bb].w);
      }
    }
  }
  __shared__ float red[4][4 * 256];
#pragma unroll
  for (int bb = 0; bb < 4; ++bb) {
    red[wid][bb * 256 + lane]       = acc[bb].x;
    red[wid][bb * 256 + lane + 64]  = acc[bb].y;
    red[wid][bb * 256 + lane + 128] = acc[bb].z;
    red[wid][bb * 256 + lane + 192] = acc[bb].w;
  }
  __syncthreads();
#pragma unroll
  for (int bb = 0; bb < 4; ++bb) {
    const int idx = bb * 256 + tid;
    const float s = red[0][idx] + red[1][idx] + red[2][idx] + red[3][idx];
    s_part[((size_t)(bg * 4 + bb) * CH + ch) * 256 + tid] = s;
  }
}
__global__ __launch_bounds__(256)
void caps_reduce(const float* __restrict__ s_part, float* __restrict__ vraw,
                 float* __restrict__ vs_next, float* __restrict__ out,
                 const float* __restrict__ v_prev_raw, float scale, int mode, int nch) {
  const int b = blockIdx.x, t = threadIdx.x;
  float s = 0.f;
  for (int ch = 0; ch < nch; ++ch)
    s += s_part[((size_t)b * nch + ch) * 256 + t];
  s *= scale;
  float sq = s * s;
  sq += __shfl_xor(sq, 1); sq += __shfl_xor(sq, 2);
  sq += __shfl_xor(sq, 4); sq += __shfl_xor(sq, 8);
  const float f = sq / ((1.f + sq) * sqrtf(sq + 1e-8f));
  const float v = s * f;
  if (mode == 0) { vraw[b*256+t] = v; vs_next[b*256+t] = v * LOG2E_; }
  else if (mode == 1) { vs_next[b*256+t] = (v + v_prev_raw[b*256+t]) * LOG2E_; }
  else { out[b*256+t] = v; }
}

extern "C" void kernel_launch(void* const* d_in, const int* in_sizes, int n_in,
                              void* d_out, int out_size, void* d_ws, size_t ws_size,
                              hipStream_t stream) {
  (void)in_sizes; (void)n_in; (void)out_size;

  const float* x = (const float*)d_in[0];
  const float* W = (const float*)d_in[1];
  float* out = (float*)d_out;

  const size_t nW = (size_t)IC_ * NC_ * OD_ * ID_;   // 4 Mi
  const size_t nX = (size_t)B_ * IC_ * ID_;          // 2 Mi
  const size_t sp_bytes  = (size_t)64 * 8 * 2048 * 4;      // 4 MB
  const size_t v_bytes   = (size_t)B_ * 256 * 4;           // 128 KB
  const size_t need_mfma = sp_bytes + 2 * v_bytes + nW * 2 + nX * 2;  // ~16.3 MB

  const dim3 blk(256), gridR(B_);

  if (ws_size >= need_mfma) {
    unsigned int* spdw = (unsigned int*)d_ws;
    float* v1raw = (float*)((char*)d_ws + sp_bytes);
    float* vsb   = v1raw + (size_t)B_ * 256;
    _Float16* Wh = (_Float16*)(vsb + (size_t)B_ * 256);
    _Float16* xh = Wh + nW;

    cvt16<<<2048, blk, 0, stream>>>(W, Wh, (int)(nW / 8));
    cvt16<<<1024, blk, 0, stream>>>(x, xh, (int)(nX / 8));

    const dim3 gridP(64, 8);
    caps_mfma<true ><<<gridP, blk, 0, stream>>>(xh, Wh, nullptr, spdw);
    caps_reduce2<<<gridR, blk, 0, stream>>>(spdw, v1raw, vsb, nullptr, nullptr, 1.f/16.f, 0);
    caps_mfma<false><<<gridP, blk, 0, stream>>>(xh, Wh, vsb, spdw);
    caps_reduce2<<<gridR, blk, 0, stream>>>(spdw, nullptr, vsb, nullptr, v1raw, 1.f, 1);
    caps_mfma<false><<<gridP, blk, 0, stream>>>(xh, Wh, vsb, spdw);
    caps_reduce2<<<gridR, blk, 0, stream>>>(spdw, nullptr, nullptr, out, nullptr, 1.f, 2);
  } else {
    constexpr int CH = 32;
    float* s_part = (float*)d_ws;
    float* v1raw  = s_part + (size_t)B_ * CH * 256;
    float* vsb    = v1raw + (size_t)B_ * 256;
    const dim3 gridP(B_ / 4, CH);
    caps_pass_f32<true , CH><<<gridP, blk, 0, stream>>>(x, W, nullptr, s_part);
    caps_reduce<<<gridR, blk, 0, stream>>>(s_part, v1raw, vsb, nullptr, nullptr, 1.f/16.f, 0, CH);
    caps_pass_f32<false, CH><<<gridP, blk, 0, stream>>>(x, W, vsb, s_part);
    caps_reduce<<<gridR, blk, 0, stream>>>(s_part, nullptr, vsb, nullptr, v1raw, 1.f, 1, CH);
    caps_pass_f32<false, CH><<<gridP, blk, 0, stream>>>(x, W, vsb, s_part);
    caps_reduce<<<gridR, blk, 0, stream>>>(s_part, nullptr, nullptr, out, nullptr, 1.f, 2, CH);
  }
}